// Round 8
// baseline (315.076 us; speedup 1.0000x reference)
//
#include <hip/hip_runtime.h>
#include <stdint.h>

#define T_SEQ   2048
#define DMODEL  1024
#define NHEADS  16
#define HDIM    64
#define BATCH   4
#define MROWS   (BATCH * T_SEQ)   // 8192
// Q pre-scale: 1/sqrt(64) * log2(e)  (softmax runs in exp2 domain)
#define QSCALE  0.18033688011112042f
// defer-max threshold (log2 units): skip O/l rescale unless max grew by >6
#define DEFER_THR 6.0f

typedef __attribute__((ext_vector_type(4))) short bf16x4;
typedef __attribute__((ext_vector_type(8))) short bf16x8;
typedef __attribute__((ext_vector_type(4))) float f32x4;

__device__ __forceinline__ unsigned short f2b(float f) {
    union { float f; unsigned int i; } x;
    x.f = f;
    unsigned int r = x.i + 0x7FFFu + ((x.i >> 16) & 1u);  // RNE
    return (unsigned short)(r >> 16);
}

// raw v_exp_f32 (input in log2 domain)
__device__ __forceinline__ float fexp2(float x) {
#if __has_builtin(__builtin_amdgcn_exp2f)
    return __builtin_amdgcn_exp2f(x);
#else
    return __expf(x * 0.6931471805599453f);
#endif
}

// pack two fp32 -> packed bf16 pair (low = a, high = b)
__device__ __forceinline__ unsigned int pack2(float a, float b) {
#if __has_builtin(__builtin_amdgcn_cvt_pk_bf16_f32)
    auto r = __builtin_amdgcn_cvt_pk_bf16_f32(a, b);
    unsigned int u;
    __builtin_memcpy(&u, &r, 4);
    return u;
#else
    return ((unsigned int)f2b(a)) | (((unsigned int)f2b(b)) << 16);
#endif
}

// tree max of a 4x f32x4 tile (depth 4; clang fuses pairs to v_max3 where it can)
__device__ __forceinline__ float max16(const f32x4 s[4]) {
    const float a = fmaxf(fmaxf(s[0][0], s[0][1]), fmaxf(s[0][2], s[0][3]));
    const float b = fmaxf(fmaxf(s[1][0], s[1][1]), fmaxf(s[1][2], s[1][3]));
    const float c = fmaxf(fmaxf(s[2][0], s[2][1]), fmaxf(s[2][2], s[2][3]));
    const float d = fmaxf(fmaxf(s[3][0], s[3][1]), fmaxf(s[3][2], s[3][3]));
    return fmaxf(fmaxf(a, b), fmaxf(c, d));
}

// online softmax (exp2 domain) for one 16x(4x16) score tile
__device__ __forceinline__ void online_softmax(
    const f32x4 sg[4], float& m_, float& l_, f32x4 o_[4], bf16x4 pf_[4])
{
    float mc = max16(sg);
    mc = fmaxf(mc, __shfl_xor(mc, 16));
    mc = fmaxf(mc, __shfl_xor(mc, 32));
    if (__any(mc > m_ + DEFER_THR)) {          // defer-max: rescale rarely
        const float mn    = fmaxf(m_, mc);
        const float alpha = fexp2(m_ - mn);
        l_ *= alpha;
        #pragma unroll
        for (int dt = 0; dt < 4; dt++)
            #pragma unroll
            for (int r = 0; r < 4; r++) o_[dt][r] *= alpha;
        m_ = mn;
    }
    float ps = 0.f;
    #pragma unroll
    for (int s = 0; s < 4; s++) {
        const float p0 = fexp2(sg[s][0] - m_);
        const float p1 = fexp2(sg[s][1] - m_);
        const float p2 = fexp2(sg[s][2] - m_);
        const float p3 = fexp2(sg[s][3] - m_);
        ps += (p0 + p1) + (p2 + p3);
        uint2 u;
        u.x = pack2(p0, p1);
        u.y = pack2(p2, p3);
        pf_[s] = *(bf16x4*)&u;
    }
    ps += __shfl_xor(ps, 16);
    ps += __shfl_xor(ps, 32);
    l_ += ps;
}

// async global->LDS, 16 B per lane; dest = lds base (wave-uniform) + lane*16
__device__ __forceinline__ void gl_lds16(const unsigned short* g, unsigned short* l) {
    __builtin_amdgcn_global_load_lds(
        (const __attribute__((address_space(1))) void*)g,
        (__attribute__((address_space(3))) void*)l,
        16, 0, 0);
}

// ---------------------------------------------------------------------------
// fp32 -> bf16 elementwise convert
// ---------------------------------------------------------------------------
__global__ __launch_bounds__(256) void cvt_bf16(
    const float* __restrict__ in, unsigned short* __restrict__ out, int n)
{
    const int i = (blockIdx.x * 256 + threadIdx.x) * 4;
    if (i + 3 < n) {
        const float4 v = *(const float4*)(in + i);
        ushort4 o;
        o.x = f2b(v.x); o.y = f2b(v.y); o.z = f2b(v.z); o.w = f2b(v.w);
        *(ushort4*)(out + i) = o;
    }
}

// ---------------------------------------------------------------------------
// fp32 [K][N] -> bf16 [N][K] transpose+convert, 32x32 LDS tile
// ---------------------------------------------------------------------------
__global__ __launch_bounds__(256) void cvt_tr(
    const float* __restrict__ W, unsigned short* __restrict__ WT, int K, int N)
{
    __shared__ unsigned short s[32][33];
    const int n0 = blockIdx.x * 32, k0 = blockIdx.y * 32;
    const int tx = threadIdx.x & 31, ty = threadIdx.x >> 5;   // ty 0..7
    #pragma unroll
    for (int i = 0; i < 4; i++)
        s[ty + 8 * i][tx] = f2b(W[(size_t)(k0 + ty + 8 * i) * N + n0 + tx]);
    __syncthreads();
    #pragma unroll
    for (int i = 0; i < 4; i++)
        WT[(size_t)(n0 + ty + 8 * i) * K + k0 + tx] = s[tx][ty + 8 * i];
}

// ---------------------------------------------------------------------------
// R18: 256x256 8-phase counted-vmcnt QKV GEMM (T3+T4+T5 port, plain HIP).
// BM=BN=256, BK=64, 512 thr = 8 waves (2M x 4N), wave tile 128x64.
// LDS: 2 bufs x (A 32KB + B 32KB) = 128 KB. K-tile j computes buf[j&1];
// its 4 phases stage K-tile j+1's half-tiles into buf[j&1 ^ 1].
// vmcnt(2) ONCE per K-tile at phase 0, BEFORE the barrier (per-wave count:
// the 8 staging loads of the K-tile being consumed are all older than the 2
// just-issued) -> after the barrier ALL waves' data is LDS-visible; phase-0
// ds_reads sit after that barrier (cross-wave safety by construction).
// Raw s_barrier (no __syncthreads drain), lgkmcnt(0)+sched_barrier(0) before
// MFMA (rule #18), setprio(1) around the 16-MFMA cluster (T5, now enabled
// by the phase role-split). XOR swizzle chunk^(row&7) both sides (R14-
// verified, 0 bank conflicts).
// ---------------------------------------------------------------------------
__global__ __launch_bounds__(512, 2) void gemm_qkv8(
    const unsigned short* __restrict__ A,    // [8192][1024] bf16
    const unsigned short* __restrict__ BT,   // [3072][1024] bf16
    const float* __restrict__ bias,
    unsigned short* __restrict__ Oq,
    unsigned short* __restrict__ Ok,
    unsigned short* __restrict__ Ov)
{
    constexpr int KD = DMODEL;        // 1024
    constexpr int NK = KD / 64;       // 16 K-tiles
    __shared__ __align__(16) unsigned short aS[2 * 256 * 64];  // 64 KB
    __shared__ __align__(16) unsigned short bS[2 * 256 * 64];  // 64 KB

    const int tid   = threadIdx.x;
    const int lane  = tid & 63;
    const int wave  = tid >> 6;        // 0..7
    const int row16 = lane & 15;
    const int quadL = lane >> 4;       // 0..3
    const int wm    = wave >> 2;       // 0..1
    const int wn    = wave & 3;        // 0..3
    const int n0    = blockIdx.x * 256;
    const int m0    = blockIdx.y * 256;

    // staging geometry: one gl_lds16 (per wave) = 8 rows x 128 B
    const int lrow = lane >> 3;              // 0..7
    const int csw  = (lane & 7) ^ lrow;      // pre-swizzled source chunk

    const unsigned short* aB = A  + (size_t)(m0 + wave * 8 + lrow) * KD + csw * 8;
    const unsigned short* bB = BT + (size_t)(n0 + wave * 8 + lrow) * KD + csw * 8;
    unsigned short* aD = &aS[wave * 512];    // wave-uniform LDS dest base
    unsigned short* bD = &bS[wave * 512];

    // fragment-read swizzled chunks (row16&7 = LDS row & 7 for all frags)
    const int sw0 = (quadL)     ^ (row16 & 7);   // K-half 0
    const int sw1 = (4 + quadL) ^ (row16 & 7);   // K-half 1
    const int aO  = (wm * 128 + row16) * 64;     // + mf*1024 (+ buf*16384)
    const int bO  = (wn * 64  + row16) * 64;     // + nf*1024

    f32x4 acc[8][4];
    const f32x4 z = {0.f, 0.f, 0.f, 0.f};
    #pragma unroll
    for (int i = 0; i < 8; i++)
        #pragma unroll
        for (int j = 0; j < 4; j++) acc[i][j] = z;

    // prologue: stage K-tile 0 into buf 0 (8 calls, same order as steady state)
    gl_lds16(aB,                      aD);
    gl_lds16(aB + (size_t)64  * KD,   aD + 64  * 64);
    gl_lds16(aB + (size_t)128 * KD,   aD + 128 * 64);
    gl_lds16(aB + (size_t)192 * KD,   aD + 192 * 64);
    gl_lds16(bB,                      bD);
    gl_lds16(bB + (size_t)64  * KD,   bD + 64  * 64);
    gl_lds16(bB + (size_t)128 * KD,   bD + 128 * 64);
    gl_lds16(bB + (size_t)192 * KD,   bD + 192 * 64);

    for (int j = 0; j < NK; ++j) {
        const int rb   = (j & 1) * 16384;            // read buf (shorts)
        const int wb   = rb ^ 16384;                 // write buf
        const int ksrc = (j + 1 < NK) ? (j + 1) * 64 : 0;  // wrap: harmless re-stage
        const unsigned short* aPk = aB + ksrc;
        const unsigned short* bPk = bB + ksrc;

        bf16x8 bfr[4][2];
        bf16x8 a0, a1, a2, a3;

        // ================= phase 0 (mf 0,1) =================
        gl_lds16(aPk,                    aD + wb);
        gl_lds16(aPk + (size_t)64 * KD,  aD + wb + 64 * 64);
        asm volatile("s_waitcnt vmcnt(2)" ::: "memory");   // K-tile j fully in LDS
        __builtin_amdgcn_s_barrier();                      // ... for ALL waves
        #pragma unroll
        for (int nf = 0; nf < 4; ++nf) {
            bfr[nf][0] = *(const bf16x8*)&bS[rb + bO + nf * 1024 + sw0 * 8];
            bfr[nf][1] = *(const bf16x8*)&bS[rb + bO + nf * 1024 + sw1 * 8];
        }
        a0 = *(const bf16x8*)&aS[rb + aO + 0 * 1024 + sw0 * 8];
        a1 = *(const bf16x8*)&aS[rb + aO + 0 * 1024 + sw1 * 8];
        a2 = *(const bf16x8*)&aS[rb + aO + 1 * 1024 + sw0 * 8];
        a3 = *(const bf16x8*)&aS[rb + aO + 1 * 1024 + sw1 * 8];
        asm volatile("s_waitcnt lgkmcnt(0)" ::: "memory");
        __builtin_amdgcn_sched_barrier(0);
        __builtin_amdgcn_s_setprio(1);
        #pragma unroll
        for (int nf = 0; nf < 4; ++nf) {
            acc[0][nf] = __builtin_amdgcn_mfma_f32_16x16x32_bf16(a0, bfr[nf][0], acc[0][nf], 0, 0, 0);
            acc[0][nf] = __builtin_amdgcn_mfma_f32_16x16x32_bf16(a1, bfr[nf][1], acc[0][nf], 0, 0, 0);
            acc[1][nf] = __builtin_amdgcn_mfma_f32_16x16x32_bf16(a2, bfr[nf][0], acc[1][nf], 0, 0, 0);
            acc[1][nf] = __builtin_amdgcn_mfma_f32_16x16x32_bf16(a3, bfr[nf][1], acc[1][nf], 0, 0, 0);
        }
        __builtin_amdgcn_s_setprio(0);
        __builtin_amdgcn_s_barrier();

        // ================= phase 1 (mf 2,3) =================
        gl_lds16(aPk + (size_t)128 * KD, aD + wb + 128 * 64);
        gl_lds16(aPk + (size_t)192 * KD, aD + wb + 192 * 64);
        a0 = *(const bf16x8*)&aS[rb + aO + 2 * 1024 + sw0 * 8];
        a1 = *(const bf16x8*)&aS[rb + aO + 2 * 1024 + sw1 * 8];
        a2 = *(const bf16x8*)&aS[rb + aO + 3 * 1024 + sw0 * 8];
        a3 = *(const bf16x8*)&aS[rb + aO + 3 * 1024 + sw1 * 8];
        __builtin_amdgcn_s_barrier();
        asm volatile("s_waitcnt lgkmcnt(0)" ::: "memory");
        __builtin_amdgcn_sched_barrier(0);
        __builtin_amdgcn_s_setprio(1);
        #pragma unroll
        for (int nf = 0; nf < 4; ++nf) {
            acc[2][nf] = __builtin_amdgcn_mfma_f32_16x16x32_bf16(a0, bfr[nf][0], acc[2][nf], 0, 0, 0);
            acc[2][nf] = __builtin_amdgcn_mfma_f32_16x16x32_bf16(a1, bfr[nf][1], acc[2][nf], 0, 0, 0);
            acc[3][nf] = __builtin_amdgcn_mfma_f32_16x16x32_bf16(a2, bfr[nf][0], acc[3][nf], 0, 0, 0);
            acc[3][nf] = __builtin_amdgcn_mfma_f32_16x16x32_bf16(a3, bfr[nf][1], acc[3][nf], 0, 0, 0);
        }
        __builtin_amdgcn_s_setprio(0);
        __builtin_amdgcn_s_barrier();

        // ================= phase 2 (mf 4,5) =================
        gl_lds16(bPk,                    bD + wb);
        gl_lds16(bPk + (size_t)64 * KD,  bD + wb + 64 * 64);
        a0 = *(const bf16x8*)&aS[rb + aO + 4 * 1024 + sw0 * 8];
        a1 = *(const bf16x8*)&aS[rb + aO + 4 * 1024 + sw1 * 8];
        a2 = *(const bf16x8*)&aS[rb + aO + 5 * 1024 + sw0 * 8];
        a3 = *(const bf16x8*)&aS[rb + aO + 5 * 1024 + sw1 * 8];
        __builtin_amdgcn_s_barrier();
        asm volatile("s_waitcnt lgkmcnt(0)" ::: "memory");
        __builtin_amdgcn_sched_barrier(0);
        __builtin_amdgcn_s_setprio(1);
        #pragma unroll
        for (int nf = 0; nf < 4; ++nf) {
            acc[4][nf] = __builtin_amdgcn_mfma_f32_16x16x32_bf16(a0, bfr[nf][0], acc[4][nf], 0, 0, 0);
            acc[4][nf] = __builtin_amdgcn_mfma_f32_16x16x32_bf16(a1, bfr[nf][1], acc[4][nf], 0, 0, 0);
            acc[5][nf] = __builtin_amdgcn_mfma_f32_16x16x32_bf16(a2, bfr[nf][0], acc[5][nf], 0, 0, 0);
            acc[5][nf] = __builtin_amdgcn_mfma_f32_16x16x32_bf16(a3, bfr[nf][1], acc[5][nf], 0, 0, 0);
        }
        __builtin_amdgcn_s_setprio(0);
        __builtin_amdgcn_s_barrier();

        // ================= phase 3 (mf 6,7) =================
        gl_lds16(bPk + (size_t)128 * KD, bD + wb + 128 * 64);
        gl_lds16(bPk + (size_t)192 * KD, bD + wb + 192 * 64);
        a0 = *(const bf16x8*)&aS[rb + aO + 6 * 1024 + sw0 * 8];
        a1 = *(const bf16x8*)&aS[rb + aO + 6 * 1024 + sw1 * 8];
        a2 = *(const bf16x8*)&aS[rb + aO + 7 * 1024 + sw0 * 8];
        a3 = *(const bf16x8*)&aS[rb + aO + 7 * 1024 + sw1 * 8];
        __builtin_amdgcn_s_barrier();
        asm volatile("s_waitcnt lgkmcnt(0)" ::: "memory");
        __builtin_amdgcn_sched_barrier(0);
        __builtin_amdgcn_s_setprio(1);
        #pragma unroll
        for (int nf = 0; nf < 4; ++nf) {
            acc[6][nf] = __builtin_amdgcn_mfma_f32_16x16x32_bf16(a0, bfr[nf][0], acc[6][nf], 0, 0, 0);
            acc[6][nf] = __builtin_amdgcn_mfma_f32_16x16x32_bf16(a1, bfr[nf][1], acc[6][nf], 0, 0, 0);
            acc[7][nf] = __builtin_amdgcn_mfma_f32_16x16x32_bf16(a2, bfr[nf][0], acc[7][nf], 0, 0, 0);
            acc[7][nf] = __builtin_amdgcn_mfma_f32_16x16x32_bf16(a3, bfr[nf][1], acc[7][nf], 0, 0, 0);
        }
        __builtin_amdgcn_s_setprio(0);
        __builtin_amdgcn_s_barrier();
    }

    // ---- epilogue: Q (scaled) / K / V^T scatter ----
    #pragma unroll
    for (int nf = 0; nf < 4; ++nf) {
        const int n  = n0 + wn * 64 + nf * 16 + row16;
        const float bi = bias[n];
        const int which = n >> 10;
        const int rem   = n & 1023;
        const int hh    = rem >> 6;
        const int d     = rem & 63;
        #pragma unroll
        for (int mf = 0; mf < 8; ++mf) {
            const int mbase = m0 + wm * 128 + mf * 16 + quadL * 4;
            #pragma unroll
            for (int r = 0; r < 4; ++r) {
                const int mm = mbase + r;
                const int bb = mm >> 11;
                const int t  = mm & 2047;
                const int bh = bb * NHEADS + hh;
                const float v = acc[mf][nf][r] + bi;
                if (which == 0) {
                    Oq[((size_t)bh * T_SEQ + t) * HDIM + d] = f2b(v * QSCALE);
                } else if (which == 1) {
                    Ok[((size_t)bh * T_SEQ + t) * HDIM + d] = f2b(v);
                } else {
                    Ov[((size_t)bh * HDIM + d) * T_SEQ + t] = f2b(v);
                }
            }
        }
    }
}

// ---------------------------------------------------------------------------
// bf16 MFMA GEMM (128x128, BK=64, 2-barrier) — retained for the PROJ matmul
// (its 256^2 grid would be 128 blocks < 256 CUs). Verified R14/R17.
// ---------------------------------------------------------------------------
template<int KD, int NCOLS>
__global__ __launch_bounds__(256) void gemm_mfma(
    const unsigned short* __restrict__ A,
    const unsigned short* __restrict__ BT,
    const float* __restrict__ bias,
    float* __restrict__ Of)
{
    __shared__ __align__(16) unsigned short aS[128 * 64];
    __shared__ __align__(16) unsigned short bS[128 * 64];

    const int tid  = threadIdx.x;
    const int lane = tid & 63;
    const int wave = tid >> 6;
    const int row  = lane & 15;
    const int quad = lane >> 4;
    const int wm   = wave >> 1;
    const int wn   = wave & 1;
    const int m0   = blockIdx.y * 128;
    const int n0   = blockIdx.x * 128;

    const int srow = lane >> 3;            // 0..7  local row
    const int c8   = lane & 7;             // 0..7  dest chunk (16B units)
    const int csw  = c8 ^ srow;            // pre-swizzled SOURCE chunk

    const unsigned short* aG = A  + (size_t)(m0 + wave * 8 + srow) * KD + csw * 8;
    const unsigned short* bG = BT + (size_t)(n0 + wave * 8 + srow) * KD + csw * 8;

    f32x4 acc[4][4];
    const f32x4 z = {0.f, 0.f, 0.f, 0.f};
    #pragma unroll
    for (int i = 0; i < 4; i++)
        #pragma unroll
        for (int j = 0; j < 4; j++) acc[i][j] = z;

    for (int k0 = 0; k0 < KD; k0 += 64) {
        __syncthreads();   // all waves done reading previous tile
        #pragma unroll
        for (int c = 0; c < 4; c++) {
            gl_lds16(aG + c * (32 * KD), &aS[c * 2048 + wave * 512]);
            gl_lds16(bG + c * (32 * KD), &bS[c * 2048 + wave * 512]);
        }
        __syncthreads();   // drains vmcnt -> LDS valid
        aG += 64;
        bG += 64;

        #pragma unroll
        for (int ks = 0; ks < 2; ks++) {
            bf16x8 af[4], bf[4];
            const int cp = ((ks * 4 + quad) ^ (row & 7)) * 8;   // swizzled read chunk
            #pragma unroll
            for (int t = 0; t < 4; t++) {
                af[t] = *(const bf16x8*)(aS + (wm * 64 + t * 16 + row) * 64 + cp);
                bf[t] = *(const bf16x8*)(bS + (wn * 64 + t * 16 + row) * 64 + cp);
            }
            #pragma unroll
            for (int i = 0; i < 4; i++)
                #pragma unroll
                for (int j = 0; j < 4; j++)
                    acc[i][j] = __builtin_amdgcn_mfma_f32_16x16x32_bf16(af[i], bf[j], acc[i][j], 0, 0, 0);
        }
    }

    #pragma unroll
    for (int j = 0; j < 4; j++) {
        const int n  = n0 + wn * 64 + j * 16 + row;
        const float bi = bias[n];
        #pragma unroll
        for (int i = 0; i < 4; i++) {
            const int mbase = m0 + wm * 64 + i * 16 + quad * 4;
            #pragma unroll
            for (int r = 0; r < 4; r++)
                Of[(size_t)(mbase + r) * NCOLS + n] = acc[i][j][r] + bi;
        }
    }
}

// ---------------------------------------------------------------------------
// MFMA flash attention — R16 (verified): 8-wave blocks, 2 tiles/wave,
// mirrored per-wave. 200 iters/head; 512 thr, launch_bounds(512,4) ->
// 16 waves/CU. kf/vf shared by the wave's two tiles. Defer-max + tree-max.
// ---------------------------------------------------------------------------
__global__ __launch_bounds__(512, 4) void attn_mfma(
    const unsigned short* __restrict__ Q,   // [bh][t][64] bf16 (scaled, log2e)
    const unsigned short* __restrict__ K,   // [bh][t][64] bf16
    const unsigned short* __restrict__ VT,  // [bh][64][T] bf16
    unsigned short* __restrict__ Out)       // [B*T][DMODEL] bf16
{
    __shared__ __align__(16) unsigned short kS[2][64 * 72];
    __shared__ __align__(16) unsigned short vS[2][64 * 72];

    const int tid  = threadIdx.x;
    const int lane = tid & 63;
    const int wave = tid >> 6;       // 0..7
    const int row  = lane & 15;
    const int quad = lane >> 4;

    const int bh = blockIdx.x;
    const int b  = bh >> 4;
    const int h  = bh & 15;
    const int P  = blockIdx.y;                 // 0..7
    const int q0H = 128 * (15 - P) + 16 * wave;   // upper-half tile
    const int q0L = 128 * P        + 16 * wave;   // lower-half tile
    const int kend = 128 * (15 - P) + 128;        // WG-uniform loop bound

    const size_t qkbase = (size_t)bh * T_SEQ * HDIM;
    const size_t vtbase = (size_t)bh * HDIM * T_SEQ;

    // staging geometry: 512 threads cover one 64x64 tile per operand
    const int krow0 = tid >> 3;          // 0..63
    const int c0    = tid & 7;           // 0..7
    const int lds0  = krow0 * 72 + c0 * 8;
    const int flat0 = tid * 8;           // = krow0*64 + c0*8

    // Q fragments
    const unsigned short* qpH = Q + qkbase + (size_t)(q0H + row) * HDIM + quad * 8;
    const bf16x8 qH0 = *(const bf16x8*)qpH;
    const bf16x8 qH1 = *(const bf16x8*)(qpH + 32);
    const unsigned short* qpL = Q + qkbase + (size_t)(q0L + row) * HDIM + quad * 8;
    const bf16x8 qL0 = *(const bf16x8*)qpL;
    const bf16x8 qL1 = *(const bf16x8*)(qpL + 32);

    const f32x4 z = {0.f, 0.f, 0.f, 0.f};
    f32x4 oH[4] = {z, z, z, z};
    f32x4 oL[4] = {z, z, z, z};
    float mH = -1e30f, lH = 0.f, mL = -1e30f, lL = 0.f;

    // prefetch tile 0
    uint4 pk0 = *(const uint4*)(K  + qkbase + flat0);
    uint4 pv0 = *(const uint4*)(VT + vtbase + (size_t)krow0 * T_SEQ + c0 * 8);

    int buf = 0;
    for (int kb = 0; kb < kend; kb += 64) {
        // write staged tile to LDS[buf]
        *(uint4*)&kS[buf][lds0] = pk0;
        *(uint4*)&vS[buf][lds0] = pv0;
        __syncthreads();

        // prefetch next tile (overlaps with compute below)
        if (kb + 64 < kend) {
            const int kn = kb + 64;
            pk0 = *(const uint4*)(K  + qkbase + (size_t)kn * HDIM + flat0);
            pv0 = *(const uint4*)(VT + vtbase + (size_t)krow0 * T_SEQ + kn + c0 * 8);
        }

        const bool actH = (kb <= q0H);       // wave-uniform
        const bool actL = (kb <= q0L);       // wave-uniform

        bf16x4 pfH[4], pfL[4];               // written iff actH / actL

        if (actH) {
            // ---- QK^T from LDS K tile (kf shared by H and L) ----
            f32x4 sH[4], sL[4];
            #pragma unroll
            for (int s = 0; s < 4; s++) {
                const int kbs = kb + s * 16;
                if (kbs <= q0H) {
                    const unsigned short* kp = &kS[buf][(s * 16 + row) * 72 + quad * 8];
                    const bf16x8 kf0 = *(const bf16x8*)kp;
                    const bf16x8 kf1 = *(const bf16x8*)(kp + 32);
                    f32x4 t = z;
                    t = __builtin_amdgcn_mfma_f32_16x16x32_bf16(kf0, qH0, t, 0, 0, 0);
                    t = __builtin_amdgcn_mfma_f32_16x16x32_bf16(kf1, qH1, t, 0, 0, 0);
                    if (kbs == q0H) {
                        #pragma unroll
                        for (int r = 0; r < 4; r++)
                            if (quad * 4 + r > row) t[r] = -1e30f;
                    }
                    sH[s] = t;
                    if (kbs <= q0L) {
                        f32x4 u = z;
                        u = __builtin_amdgcn_mfma_f32_16x16x32_bf16(kf0, qL0, u, 0, 0, 0);
                        u = __builtin_amdgcn_mfma_f32_16x16x32_bf16(kf1, qL1, u, 0, 0, 0);
                        if (kbs == q0L) {
                            #pragma unroll
                            for (int r = 0; r < 4; r++)
                                if (quad * 4 + r > row) u[r] = -1e30f;
                        }
                        sL[s] = u;
                    } else {
                        #pragma unroll
                        for (int r = 0; r < 4; r++) sL[s][r] = -1e30f;
                    }
                } else {
                    #pragma unroll
                    for (int r = 0; r < 4; r++) { sH[s][r] = -1e30f; sL[s][r] = -1e30f; }
                }
            }
            online_softmax(sH, mH, lH, oH, pfH);
            if (actL)
                online_softmax(sL, mL, lL, oL, pfL);

            // ---- PV from LDS V^T tile: vf shared by H and L ----
            #pragma unroll
            for (int s = 0; s < 4; s++) {
                const int kbs = kb + s * 16;
                if (kbs <= q0H) {
                    #pragma unroll
                    for (int dt = 0; dt < 4; dt++) {
                        const bf16x4 vf = *(const bf16x4*)&vS[buf][
                            (dt * 16 + row) * 72 + (s * 2 + (quad >> 1)) * 8 + (quad & 1) * 4];
                        oH[dt] = __builtin_amdgcn_mfma_f32_16x16x16bf16_1k(vf, pfH[s], oH[dt], 0, 0, 0);
                        if (kbs <= q0L)
                            oL[dt] = __builtin_amdgcn_mfma_f32_16x16x16bf16_1k(vf, pfL[s], oL[dt], 0, 0, 0);
                    }
                }
            }
        }

        buf ^= 1;
    }

    // ---- epilogue: both tiles ----
    {
        const float rl = 1.f / lH;
        unsigned short* op = Out + ((size_t)(b * T_SEQ + q0H + row)) * DMODEL + h * HDIM + quad * 4;
        #pragma unroll
        for (int dt = 0; dt < 4; dt++) {
            uint2 u;
            u.x = pack2(oH[dt][0] * rl, oH[dt][1] * rl);
            u.y = pack2(oH[dt][2] * rl, oH[dt][3] * rl);
            *(uint2*)(op + dt * 16) = u;
        }
    }
    {
        const float rl = 1.f / lL;
        unsigned short* op = Out + ((size_t)(b * T_SEQ + q0L + row)) * DMODEL + h * HDIM + quad * 4;
        #pragma unroll
        for (int dt = 0; dt < 4; dt++) {
            uint2 u;
            u.x = pack2(oL[dt][0] * rl, oL[dt][1] * rl);
            u.y = pack2(oL[dt][2] * rl, oL[dt][3] * rl);
            *(uint2*)(op + dt * 16) = u;
        }
    }
}

extern "C" void kernel_launch(void* const* d_in, const int* in_sizes, int n_in,
                              void* d_out, int out_size, void* d_ws, size_t ws_size,
                              hipStream_t stream)
{
    const float* x    = (const float*)d_in[0];
    const float* Wqkv = (const float*)d_in[1];
    const float* bqkv = (const float*)d_in[2];
    const float* Wout = (const float*)d_in[3];
    const float* bout = (const float*)d_in[4];
    float* out = (float*)d_out;

    // workspace (MiB offsets): xb 0..16 | WqkvT 16..22 | WoutT 22..24 |
    // Qb 24..40 | Kb 40..56 | Vt 56..72 | Ab 72..88
    char* ws = (char*)d_ws;
    unsigned short* xb    = (unsigned short*)(ws + (size_t)0  * 1024 * 1024);
    unsigned short* WqkvT = (unsigned short*)(ws + (size_t)16 * 1024 * 1024);
    unsigned short* WoutT = (unsigned short*)(ws + (size_t)22 * 1024 * 1024);
    unsigned short* Qb    = (unsigned short*)(ws + (size_t)24 * 1024 * 1024);
    unsigned short* Kb    = (unsigned short*)(ws + (size_t)40 * 1024 * 1024);
    unsigned short* Vt    = (unsigned short*)(ws + (size_t)56 * 1024 * 1024);
    unsigned short* Ab    = (unsigned short*)(ws + (size_t)72 * 1024 * 1024);

    // 0) converts / transposes
    cvt_bf16<<<dim3(MROWS * DMODEL / 1024), 256, 0, stream>>>(x, xb, MROWS * DMODEL);
    cvt_tr<<<dim3(3 * DMODEL / 32, DMODEL / 32), 256, 0, stream>>>(Wqkv, WqkvT, DMODEL, 3 * DMODEL);
    cvt_tr<<<dim3(DMODEL / 32, DMODEL / 32), 256, 0, stream>>>(Wout, WoutT, DMODEL, DMODEL);

    // 1) qkv = x @ W_qkv + b_qkv -> Qb (scaled, log2e folded), Kb, Vt
    //    256^2 8-phase counted-vmcnt schedule, grid 12x32
    gemm_qkv8<<<dim3(3 * DMODEL / 256, MROWS / 256), 512, 0, stream>>>(
        xb, WqkvT, bqkv, Qb, Kb, Vt);

    // 2) causal MFMA flash attention -> Ab bf16 (8 blocks/head, 8 waves each)
    attn_mfma<<<dim3(BATCH * NHEADS, 8), 512, 0, stream>>>(Qb, Kb, Vt, Ab);

    // 3) out = Ab @ W_out + b_out (fp32 out), verified 128^2 path
    gemm_mfma<DMODEL, DMODEL><<<dim3(DMODEL / 128, MROWS / 128), 256, 0, stream>>>(
        Ab, WoutT, bout, out);
}

// Round 9
// 281.158 us; speedup vs baseline: 1.1206x; 1.1206x over previous
//
#include <hip/hip_runtime.h>
#include <stdint.h>

#define T_SEQ   2048
#define DMODEL  1024
#define NHEADS  16
#define HDIM    64
#define BATCH   4
#define MROWS   (BATCH * T_SEQ)   // 8192
// Q pre-scale: 1/sqrt(64) * log2(e)  (softmax runs in exp2 domain)
#define QSCALE  0.18033688011112042f
// defer-max threshold (log2 units): skip O/l rescale unless max grew by >6
#define DEFER_THR 6.0f

typedef __attribute__((ext_vector_type(4))) short bf16x4;
typedef __attribute__((ext_vector_type(8))) short bf16x8;
typedef __attribute__((ext_vector_type(4))) float f32x4;

__device__ __forceinline__ unsigned short f2b(float f) {
    union { float f; unsigned int i; } x;
    x.f = f;
    unsigned int r = x.i + 0x7FFFu + ((x.i >> 16) & 1u);  // RNE
    return (unsigned short)(r >> 16);
}

// raw v_exp_f32 (input in log2 domain)
__device__ __forceinline__ float fexp2(float x) {
#if __has_builtin(__builtin_amdgcn_exp2f)
    return __builtin_amdgcn_exp2f(x);
#else
    return __expf(x * 0.6931471805599453f);
#endif
}

// pack two fp32 -> packed bf16 pair (low = a, high = b)
__device__ __forceinline__ unsigned int pack2(float a, float b) {
#if __has_builtin(__builtin_amdgcn_cvt_pk_bf16_f32)
    auto r = __builtin_amdgcn_cvt_pk_bf16_f32(a, b);
    unsigned int u;
    __builtin_memcpy(&u, &r, 4);
    return u;
#else
    return ((unsigned int)f2b(a)) | (((unsigned int)f2b(b)) << 16);
#endif
}

// tree max of a 4x f32x4 tile (depth 4; clang fuses pairs to v_max3 where it can)
__device__ __forceinline__ float max16(const f32x4 s[4]) {
    const float a = fmaxf(fmaxf(s[0][0], s[0][1]), fmaxf(s[0][2], s[0][3]));
    const float b = fmaxf(fmaxf(s[1][0], s[1][1]), fmaxf(s[1][2], s[1][3]));
    const float c = fmaxf(fmaxf(s[2][0], s[2][1]), fmaxf(s[2][2], s[2][3]));
    const float d = fmaxf(fmaxf(s[3][0], s[3][1]), fmaxf(s[3][2], s[3][3]));
    return fmaxf(fmaxf(a, b), fmaxf(c, d));
}

// online softmax (exp2 domain) for one 16x(4x16) score tile
__device__ __forceinline__ void online_softmax(
    const f32x4 sg[4], float& m_, float& l_, f32x4 o_[4], bf16x4 pf_[4])
{
    float mc = max16(sg);
    mc = fmaxf(mc, __shfl_xor(mc, 16));
    mc = fmaxf(mc, __shfl_xor(mc, 32));
    if (__any(mc > m_ + DEFER_THR)) {          // defer-max: rescale rarely
        const float mn    = fmaxf(m_, mc);
        const float alpha = fexp2(m_ - mn);
        l_ *= alpha;
        #pragma unroll
        for (int dt = 0; dt < 4; dt++)
            #pragma unroll
            for (int r = 0; r < 4; r++) o_[dt][r] *= alpha;
        m_ = mn;
    }
    float ps = 0.f;
    #pragma unroll
    for (int s = 0; s < 4; s++) {
        const float p0 = fexp2(sg[s][0] - m_);
        const float p1 = fexp2(sg[s][1] - m_);
        const float p2 = fexp2(sg[s][2] - m_);
        const float p3 = fexp2(sg[s][3] - m_);
        ps += (p0 + p1) + (p2 + p3);
        uint2 u;
        u.x = pack2(p0, p1);
        u.y = pack2(p2, p3);
        pf_[s] = *(bf16x4*)&u;
    }
    ps += __shfl_xor(ps, 16);
    ps += __shfl_xor(ps, 32);
    l_ += ps;
}

// async global->LDS, 16 B per lane; dest = lds base (wave-uniform) + lane*16
__device__ __forceinline__ void gl_lds16(const unsigned short* g, unsigned short* l) {
    __builtin_amdgcn_global_load_lds(
        (const __attribute__((address_space(1))) void*)g,
        (__attribute__((address_space(3))) void*)l,
        16, 0, 0);
}

// ---------------------------------------------------------------------------
// fp32 -> bf16 elementwise convert
// ---------------------------------------------------------------------------
__global__ __launch_bounds__(256) void cvt_bf16(
    const float* __restrict__ in, unsigned short* __restrict__ out, int n)
{
    const int i = (blockIdx.x * 256 + threadIdx.x) * 4;
    if (i + 3 < n) {
        const float4 v = *(const float4*)(in + i);
        ushort4 o;
        o.x = f2b(v.x); o.y = f2b(v.y); o.z = f2b(v.z); o.w = f2b(v.w);
        *(ushort4*)(out + i) = o;
    }
}

// ---------------------------------------------------------------------------
// fp32 [K][N] -> bf16 [N][K] transpose+convert, 32x32 LDS tile
// ---------------------------------------------------------------------------
__global__ __launch_bounds__(256) void cvt_tr(
    const float* __restrict__ W, unsigned short* __restrict__ WT, int K, int N)
{
    __shared__ unsigned short s[32][33];
    const int n0 = blockIdx.x * 32, k0 = blockIdx.y * 32;
    const int tx = threadIdx.x & 31, ty = threadIdx.x >> 5;   // ty 0..7
    #pragma unroll
    for (int i = 0; i < 4; i++)
        s[ty + 8 * i][tx] = f2b(W[(size_t)(k0 + ty + 8 * i) * N + n0 + tx]);
    __syncthreads();
    #pragma unroll
    for (int i = 0; i < 4; i++)
        WT[(size_t)(n0 + ty + 8 * i) * K + k0 + tx] = s[tx][ty + 8 * i];
}

// ---------------------------------------------------------------------------
// bf16 MFMA GEMM: C[M][NCOLS] = A[M][KD] * BT[NCOLS][KD]^T + bias[NCOLS]
// 128x128 tile, BK=64, 256 thr = 4 waves (2x2). VERIFIED R17 (293.7 total).
// R19: 256^2 8-phase reverted — at K=1024 / 1 block/CU it was latency-bound
// (MfmaUtil 16, VALUBusy 11, occ 15): the 2-buffer LDS can't hold a >=2-tile
// prefetch lead, so every K-tile stalls ~800cy at its phase-0 vmcnt.
// Compile-time KD/NCOLS + hoisted staging pointers (R17 win, QKV ~93us).
// XOR swizzle chunk^(row&7), source-side + read-side (0 bank conflicts).
// ---------------------------------------------------------------------------
template<int KD, int NCOLS, int MODE>
__global__ __launch_bounds__(256) void gemm_mfma(
    const unsigned short* __restrict__ A,
    const unsigned short* __restrict__ BT,
    const float* __restrict__ bias,
    unsigned short* __restrict__ Oq,
    unsigned short* __restrict__ Ok,
    unsigned short* __restrict__ Ov,
    float* __restrict__ Of)
{
    __shared__ __align__(16) unsigned short aS[128 * 64];
    __shared__ __align__(16) unsigned short bS[128 * 64];

    const int tid  = threadIdx.x;
    const int lane = tid & 63;
    const int wave = tid >> 6;
    const int row  = lane & 15;
    const int quad = lane >> 4;
    const int wm   = wave >> 1;
    const int wn   = wave & 1;
    const int m0   = blockIdx.y * 128;
    const int n0   = blockIdx.x * 128;

    // staging geometry: one gload = 64 lanes x 16B = 8 rows x 64 k (128B/row)
    const int srow = lane >> 3;            // 0..7  local row
    const int c8   = lane & 7;             // 0..7  dest chunk (16B units)
    const int csw  = c8 ^ srow;            // pre-swizzled SOURCE chunk

    // hoisted global staging pointers (advance by 64 elements per K-step)
    const unsigned short* aG = A  + (size_t)(m0 + wave * 8 + srow) * KD + csw * 8;
    const unsigned short* bG = BT + (size_t)(n0 + wave * 8 + srow) * KD + csw * 8;

    f32x4 acc[4][4];
    const f32x4 z = {0.f, 0.f, 0.f, 0.f};
    #pragma unroll
    for (int i = 0; i < 4; i++)
        #pragma unroll
        for (int j = 0; j < 4; j++) acc[i][j] = z;

    for (int k0 = 0; k0 < KD; k0 += 64) {
        __syncthreads();   // all waves done reading previous tile
        #pragma unroll
        for (int c = 0; c < 4; c++) {
            gl_lds16(aG + c * (32 * KD), &aS[c * 2048 + wave * 512]);
            gl_lds16(bG + c * (32 * KD), &bS[c * 2048 + wave * 512]);
        }
        __syncthreads();   // drains vmcnt -> LDS valid
        aG += 64;
        bG += 64;

        #pragma unroll
        for (int ks = 0; ks < 2; ks++) {
            bf16x8 af[4], bf[4];
            const int cp = ((ks * 4 + quad) ^ (row & 7)) * 8;   // swizzled read chunk
            #pragma unroll
            for (int t = 0; t < 4; t++) {
                af[t] = *(const bf16x8*)(aS + (wm * 64 + t * 16 + row) * 64 + cp);
                bf[t] = *(const bf16x8*)(bS + (wn * 64 + t * 16 + row) * 64 + cp);
            }
            #pragma unroll
            for (int i = 0; i < 4; i++)
                #pragma unroll
                for (int j = 0; j < 4; j++)
                    acc[i][j] = __builtin_amdgcn_mfma_f32_16x16x32_bf16(af[i], bf[j], acc[i][j], 0, 0, 0);
        }
    }

    if (MODE == 0) {
        #pragma unroll
        for (int j = 0; j < 4; j++) {
            const int n  = n0 + wn * 64 + j * 16 + row;
            const float bi = bias[n];
            const int which = n >> 10;
            const int rem   = n & 1023;
            const int h     = rem >> 6;
            const int d     = rem & 63;
            #pragma unroll
            for (int i = 0; i < 4; i++) {
                const int mbase = m0 + wm * 64 + i * 16 + quad * 4;
                #pragma unroll
                for (int r = 0; r < 4; r++) {
                    const int m = mbase + r;
                    const int b = m >> 11;
                    const int t = m & 2047;
                    const int bh = b * NHEADS + h;
                    const float v = acc[i][j][r] + bi;
                    if (which == 0) {
                        Oq[((size_t)bh * T_SEQ + t) * HDIM + d] = f2b(v * QSCALE);
                    } else if (which == 1) {
                        Ok[((size_t)bh * T_SEQ + t) * HDIM + d] = f2b(v);
                    } else {
                        Ov[((size_t)bh * HDIM + d) * T_SEQ + t] = f2b(v);
                    }
                }
            }
        }
    } else {
        #pragma unroll
        for (int j = 0; j < 4; j++) {
            const int n  = n0 + wn * 64 + j * 16 + row;
            const float bi = bias[n];
            #pragma unroll
            for (int i = 0; i < 4; i++) {
                const int mbase = m0 + wm * 64 + i * 16 + quad * 4;
                #pragma unroll
                for (int r = 0; r < 4; r++)
                    Of[(size_t)(mbase + r) * NCOLS + n] = acc[i][j][r] + bi;
            }
        }
    }
}

// ---------------------------------------------------------------------------
// MFMA flash attention — R19: ONE tile per wave, one-sided blocks.
// Block (bh, by): i = 15-by (longest first), covers q-rows [128i, 128i+128)
// with 8 waves x 16 rows; kend = 128(i+1). Grid 64x16 = 1024 blocks ->
// 4 blocks/CU co-resident (LDS 36.9KB, VGPR target <=80) -> up to 32
// waves/CU, double R16's 16. Rationale (R7 counters + arithmetic): per
// tile-iter each pipe needs only ~120cy, yet attn ran 10x slower -> each
// wave is a serial dep chain (ds_read->MFMA->max->exp2->MFMA); only
// occupancy hides it. Total tile-iters are causally invariant vs R16
// (two-tile sharing only packed them); x2 wave count wins.
// Imbalanced block lengths (2..32 iters) amortize over 4 scheduler rounds,
// longest dispatched first. Defer-max + tree-max kept; no setprio.
// ---------------------------------------------------------------------------
__global__ __launch_bounds__(512, 4) void attn_mfma(
    const unsigned short* __restrict__ Q,   // [bh][t][64] bf16 (scaled, log2e)
    const unsigned short* __restrict__ K,   // [bh][t][64] bf16
    const unsigned short* __restrict__ VT,  // [bh][64][T] bf16
    unsigned short* __restrict__ Out)       // [B*T][DMODEL] bf16
{
    __shared__ __align__(16) unsigned short kS[2][64 * 72];
    __shared__ __align__(16) unsigned short vS[2][64 * 72];

    const int tid  = threadIdx.x;
    const int lane = tid & 63;
    const int wave = tid >> 6;       // 0..7
    const int row  = lane & 15;
    const int quad = lane >> 4;

    const int bh = blockIdx.x;
    const int b  = bh >> 4;
    const int h  = bh & 15;
    const int i  = 15 - (int)blockIdx.y;       // longest blocks first
    const int q0 = 128 * i + 16 * wave;        // this wave's 16 q-rows
    const int kend = 128 * i + 128;            // WG-uniform loop bound

    const size_t qkbase = (size_t)bh * T_SEQ * HDIM;
    const size_t vtbase = (size_t)bh * HDIM * T_SEQ;

    // staging geometry: 512 threads cover one 64x64 tile per operand
    const int krow0 = tid >> 3;          // 0..63
    const int c0    = tid & 7;           // 0..7
    const int lds0  = krow0 * 72 + c0 * 8;
    const int flat0 = tid * 8;           // = krow0*64 + c0*8

    // Q fragments
    const unsigned short* qp = Q + qkbase + (size_t)(q0 + row) * HDIM + quad * 8;
    const bf16x8 qf0 = *(const bf16x8*)qp;
    const bf16x8 qf1 = *(const bf16x8*)(qp + 32);

    const f32x4 z = {0.f, 0.f, 0.f, 0.f};
    f32x4 o[4] = {z, z, z, z};
    float m_ = -1e30f, l_ = 0.f;

    // prefetch tile 0
    uint4 pk0 = *(const uint4*)(K  + qkbase + flat0);
    uint4 pv0 = *(const uint4*)(VT + vtbase + (size_t)krow0 * T_SEQ + c0 * 8);

    int buf = 0;
    for (int kb = 0; kb < kend; kb += 64) {
        // write staged tile to LDS[buf]
        *(uint4*)&kS[buf][lds0] = pk0;
        *(uint4*)&vS[buf][lds0] = pv0;
        __syncthreads();

        // prefetch next tile (overlaps with compute below)
        if (kb + 64 < kend) {
            const int kn = kb + 64;
            pk0 = *(const uint4*)(K  + qkbase + (size_t)kn * HDIM + flat0);
            pv0 = *(const uint4*)(VT + vtbase + (size_t)krow0 * T_SEQ + kn + c0 * 8);
        }

        const bool act = (kb <= q0);         // wave-uniform

        if (act) {
            // ---- QK^T from LDS K tile ----
            f32x4 sg[4];
            bf16x4 pf[4];
            #pragma unroll
            for (int s = 0; s < 4; s++) {
                const int kbs = kb + s * 16;
                if (kbs <= q0) {
                    const unsigned short* kp = &kS[buf][(s * 16 + row) * 72 + quad * 8];
                    const bf16x8 kf0 = *(const bf16x8*)kp;
                    const bf16x8 kf1 = *(const bf16x8*)(kp + 32);
                    f32x4 t = z;
                    t = __builtin_amdgcn_mfma_f32_16x16x32_bf16(kf0, qf0, t, 0, 0, 0);
                    t = __builtin_amdgcn_mfma_f32_16x16x32_bf16(kf1, qf1, t, 0, 0, 0);
                    if (kbs == q0) {
                        #pragma unroll
                        for (int r = 0; r < 4; r++)
                            if (quad * 4 + r > row) t[r] = -1e30f;
                    }
                    sg[s] = t;
                } else {
                    #pragma unroll
                    for (int r = 0; r < 4; r++) sg[s][r] = -1e30f;
                }
            }
            online_softmax(sg, m_, l_, o, pf);

            // ---- PV from LDS V^T tile ----
            #pragma unroll
            for (int s = 0; s < 4; s++) {
                const int kbs = kb + s * 16;
                if (kbs <= q0) {
                    #pragma unroll
                    for (int dt = 0; dt < 4; dt++) {
                        const bf16x4 vf = *(const bf16x4*)&vS[buf][
                            (dt * 16 + row) * 72 + (s * 2 + (quad >> 1)) * 8 + (quad & 1) * 4];
                        o[dt] = __builtin_amdgcn_mfma_f32_16x16x16bf16_1k(vf, pf[s], o[dt], 0, 0, 0);
                    }
                }
            }
        }

        buf ^= 1;
    }

    // ---- epilogue ----
    {
        const float rl = 1.f / l_;
        unsigned short* op = Out + ((size_t)(b * T_SEQ + q0 + row)) * DMODEL + h * HDIM + quad * 4;
        #pragma unroll
        for (int dt = 0; dt < 4; dt++) {
            uint2 u;
            u.x = pack2(o[dt][0] * rl, o[dt][1] * rl);
            u.y = pack2(o[dt][2] * rl, o[dt][3] * rl);
            *(uint2*)(op + dt * 16) = u;
        }
    }
}

extern "C" void kernel_launch(void* const* d_in, const int* in_sizes, int n_in,
                              void* d_out, int out_size, void* d_ws, size_t ws_size,
                              hipStream_t stream)
{
    const float* x    = (const float*)d_in[0];
    const float* Wqkv = (const float*)d_in[1];
    const float* bqkv = (const float*)d_in[2];
    const float* Wout = (const float*)d_in[3];
    const float* bout = (const float*)d_in[4];
    float* out = (float*)d_out;

    // workspace (MiB offsets): xb 0..16 | WqkvT 16..22 | WoutT 22..24 |
    // Qb 24..40 | Kb 40..56 | Vt 56..72 | Ab 72..88
    char* ws = (char*)d_ws;
    unsigned short* xb    = (unsigned short*)(ws + (size_t)0  * 1024 * 1024);
    unsigned short* WqkvT = (unsigned short*)(ws + (size_t)16 * 1024 * 1024);
    unsigned short* WoutT = (unsigned short*)(ws + (size_t)22 * 1024 * 1024);
    unsigned short* Qb    = (unsigned short*)(ws + (size_t)24 * 1024 * 1024);
    unsigned short* Kb    = (unsigned short*)(ws + (size_t)40 * 1024 * 1024);
    unsigned short* Vt    = (unsigned short*)(ws + (size_t)56 * 1024 * 1024);
    unsigned short* Ab    = (unsigned short*)(ws + (size_t)72 * 1024 * 1024);

    // 0) converts / transposes
    cvt_bf16<<<dim3(MROWS * DMODEL / 1024), 256, 0, stream>>>(x, xb, MROWS * DMODEL);
    cvt_tr<<<dim3(3 * DMODEL / 32, DMODEL / 32), 256, 0, stream>>>(Wqkv, WqkvT, DMODEL, 3 * DMODEL);
    cvt_tr<<<dim3(DMODEL / 32, DMODEL / 32), 256, 0, stream>>>(Wout, WoutT, DMODEL, DMODEL);

    // 1) qkv = x @ W_qkv + b_qkv -> Qb (scaled, log2e folded), Kb, Vt
    gemm_mfma<DMODEL, 3 * DMODEL, 0><<<dim3(3 * DMODEL / 128, MROWS / 128), 256, 0, stream>>>(
        xb, WqkvT, bqkv, Qb, Kb, Vt, nullptr);

    // 2) causal MFMA flash attention -> Ab bf16 (16 blocks/head, 8 waves, 1 tile/wave)
    attn_mfma<<<dim3(BATCH * NHEADS, 16), 512, 0, stream>>>(Qb, Kb, Vt, Ab);

    // 3) out = Ab @ W_out + b_out (fp32 out)
    gemm_mfma<DMODEL, DMODEL, 1><<<dim3(DMODEL / 128, MROWS / 128), 256, 0, stream>>>(
        Ab, WoutT, bout, nullptr, nullptr, nullptr, out);
}

// Round 10
// 267.304 us; speedup vs baseline: 1.1787x; 1.0518x over previous
//
#include <hip/hip_runtime.h>
#include <stdint.h>

#define T_SEQ   2048
#define DMODEL  1024
#define NHEADS  16
#define HDIM    64
#define BATCH   4
#define MROWS   (BATCH * T_SEQ)   // 8192
// Q pre-scale: 1/sqrt(64) * log2(e)  (softmax runs in exp2 domain)
#define QSCALE  0.18033688011112042f
// defer-max threshold (log2 units): skip O/l rescale unless max grew by >6
#define DEFER_THR 6.0f

typedef __attribute__((ext_vector_type(4))) short bf16x4;
typedef __attribute__((ext_vector_type(8))) short bf16x8;
typedef __attribute__((ext_vector_type(4))) float f32x4;

__device__ __forceinline__ unsigned short f2b(float f) {
    union { float f; unsigned int i; } x;
    x.f = f;
    unsigned int r = x.i + 0x7FFFu + ((x.i >> 16) & 1u);  // RNE
    return (unsigned short)(r >> 16);
}

// raw v_exp_f32 (input in log2 domain)
__device__ __forceinline__ float fexp2(float x) {
#if __has_builtin(__builtin_amdgcn_exp2f)
    return __builtin_amdgcn_exp2f(x);
#else
    return __expf(x * 0.6931471805599453f);
#endif
}

// pack two fp32 -> packed bf16 pair (low = a, high = b)
__device__ __forceinline__ unsigned int pack2(float a, float b) {
#if __has_builtin(__builtin_amdgcn_cvt_pk_bf16_f32)
    auto r = __builtin_amdgcn_cvt_pk_bf16_f32(a, b);
    unsigned int u;
    __builtin_memcpy(&u, &r, 4);
    return u;
#else
    return ((unsigned int)f2b(a)) | (((unsigned int)f2b(b)) << 16);
#endif
}

// tree max of a 4x f32x4 tile (depth 4; clang fuses pairs to v_max3 where it can)
__device__ __forceinline__ float max16(const f32x4 s[4]) {
    const float a = fmaxf(fmaxf(s[0][0], s[0][1]), fmaxf(s[0][2], s[0][3]));
    const float b = fmaxf(fmaxf(s[1][0], s[1][1]), fmaxf(s[1][2], s[1][3]));
    const float c = fmaxf(fmaxf(s[2][0], s[2][1]), fmaxf(s[2][2], s[2][3]));
    const float d = fmaxf(fmaxf(s[3][0], s[3][1]), fmaxf(s[3][2], s[3][3]));
    return fmaxf(fmaxf(a, b), fmaxf(c, d));
}

// online softmax (exp2 domain) for one 16x(4x16) score tile
__device__ __forceinline__ void online_softmax(
    const f32x4 sg[4], float& m_, float& l_, f32x4 o_[4], bf16x4 pf_[4])
{
    float mc = max16(sg);
    mc = fmaxf(mc, __shfl_xor(mc, 16));
    mc = fmaxf(mc, __shfl_xor(mc, 32));
    if (__any(mc > m_ + DEFER_THR)) {          // defer-max: rescale rarely
        const float mn    = fmaxf(m_, mc);
        const float alpha = fexp2(m_ - mn);
        l_ *= alpha;
        #pragma unroll
        for (int dt = 0; dt < 4; dt++)
            #pragma unroll
            for (int r = 0; r < 4; r++) o_[dt][r] *= alpha;
        m_ = mn;
    }
    float ps = 0.f;
    #pragma unroll
    for (int s = 0; s < 4; s++) {
        const float p0 = fexp2(sg[s][0] - m_);
        const float p1 = fexp2(sg[s][1] - m_);
        const float p2 = fexp2(sg[s][2] - m_);
        const float p3 = fexp2(sg[s][3] - m_);
        ps += (p0 + p1) + (p2 + p3);
        uint2 u;
        u.x = pack2(p0, p1);
        u.y = pack2(p2, p3);
        pf_[s] = *(bf16x4*)&u;
    }
    ps += __shfl_xor(ps, 16);
    ps += __shfl_xor(ps, 32);
    l_ += ps;
}

// async global->LDS, 16 B per lane; dest = lds base (wave-uniform) + lane*16
__device__ __forceinline__ void gl_lds16(const unsigned short* g, unsigned short* l) {
    __builtin_amdgcn_global_load_lds(
        (const __attribute__((address_space(1))) void*)g,
        (__attribute__((address_space(3))) void*)l,
        16, 0, 0);
}

// ---------------------------------------------------------------------------
// fp32 -> bf16 elementwise convert
// ---------------------------------------------------------------------------
__global__ __launch_bounds__(256) void cvt_bf16(
    const float* __restrict__ in, unsigned short* __restrict__ out, int n)
{
    const int i = (blockIdx.x * 256 + threadIdx.x) * 4;
    if (i + 3 < n) {
        const float4 v = *(const float4*)(in + i);
        ushort4 o;
        o.x = f2b(v.x); o.y = f2b(v.y); o.z = f2b(v.z); o.w = f2b(v.w);
        *(ushort4*)(out + i) = o;
    }
}

// ---------------------------------------------------------------------------
// fp32 [K][N] -> bf16 [N][K] transpose+convert, 32x32 LDS tile
// ---------------------------------------------------------------------------
__global__ __launch_bounds__(256) void cvt_tr(
    const float* __restrict__ W, unsigned short* __restrict__ WT, int K, int N)
{
    __shared__ unsigned short s[32][33];
    const int n0 = blockIdx.x * 32, k0 = blockIdx.y * 32;
    const int tx = threadIdx.x & 31, ty = threadIdx.x >> 5;   // ty 0..7
    #pragma unroll
    for (int i = 0; i < 4; i++)
        s[ty + 8 * i][tx] = f2b(W[(size_t)(k0 + ty + 8 * i) * N + n0 + tx]);
    __syncthreads();
    #pragma unroll
    for (int i = 0; i < 4; i++)
        WT[(size_t)(n0 + ty + 8 * i) * K + k0 + tx] = s[tx][ty + 8 * i];
}

// ---------------------------------------------------------------------------
// bf16 MFMA GEMM: C[M][NCOLS] = A[M][KD] * BT[NCOLS][KD]^T + bias[NCOLS]
// 128x128 tile, BK=64, 256 thr = 4 waves (2x2). Compile-time KD/NCOLS +
// hoisted staging pointers (R17). XOR swizzle chunk^(row&7) (0 conflicts).
// R20: XCD-aware tile remap (T1). R9 counters: FETCH 76MB vs 22MB inputs,
// MfmaUtil 21.6 / VALUBusy 20.5 -> the 2-phase vmcnt drain is the critical
// path and its length is the stage-load latency (L2 hit 200cy vs HBM-path
// 900cy). Remap: xcd = orig&7 owns a contiguous 8-M-tile chunk, walked
// N-outer/M-inner -> per-XCD L2 working set = 1 B-panel (256KB) + 8
// A-panels (2MB) < 4MB -> stage loads L2-hit -> shorter drain every K-step.
// Bijective (grid.y = 64 = 8*8, all shifts). Requires gridDim.y % 8 == 0.
// ---------------------------------------------------------------------------
template<int KD, int NCOLS, int MODE>
__global__ __launch_bounds__(256) void gemm_mfma(
    const unsigned short* __restrict__ A,
    const unsigned short* __restrict__ BT,
    const float* __restrict__ bias,
    unsigned short* __restrict__ Oq,
    unsigned short* __restrict__ Ok,
    unsigned short* __restrict__ Ov,
    float* __restrict__ Of)
{
    __shared__ __align__(16) unsigned short aS[128 * 64];
    __shared__ __align__(16) unsigned short bS[128 * 64];

    const int tid  = threadIdx.x;
    const int lane = tid & 63;
    const int wave = tid >> 6;
    const int row  = lane & 15;
    const int quad = lane >> 4;
    const int wm   = wave >> 1;
    const int wn   = wave & 1;

    // T1 XCD remap: HW dispatches linear id x-major, round-robin over 8 XCDs.
    constexpr int NT  = NCOLS / 128;          // N-tiles (24 or 8)
    constexpr int MT8 = (MROWS / 128) / 8;    // M-tiles per XCD chunk = 8
    const int orig = blockIdx.x + blockIdx.y * NT;
    const int xcd  = orig & 7;
    const int pos  = orig >> 3;               // position within XCD chunk
    const int nt   = pos >> 3;                // N-tile (pos / MT8)
    const int mtl  = pos & (MT8 - 1);         // local M-tile
    const int m0   = (xcd * MT8 + mtl) * 128;
    const int n0   = nt * 128;

    // staging geometry: one gload = 64 lanes x 16B = 8 rows x 64 k (128B/row)
    const int srow = lane >> 3;            // 0..7  local row
    const int c8   = lane & 7;             // 0..7  dest chunk (16B units)
    const int csw  = c8 ^ srow;            // pre-swizzled SOURCE chunk

    // hoisted global staging pointers (advance by 64 elements per K-step)
    const unsigned short* aG = A  + (size_t)(m0 + wave * 8 + srow) * KD + csw * 8;
    const unsigned short* bG = BT + (size_t)(n0 + wave * 8 + srow) * KD + csw * 8;

    f32x4 acc[4][4];
    const f32x4 z = {0.f, 0.f, 0.f, 0.f};
    #pragma unroll
    for (int i = 0; i < 4; i++)
        #pragma unroll
        for (int j = 0; j < 4; j++) acc[i][j] = z;

    for (int k0 = 0; k0 < KD; k0 += 64) {
        __syncthreads();   // all waves done reading previous tile
        #pragma unroll
        for (int c = 0; c < 4; c++) {
            gl_lds16(aG + c * (32 * KD), &aS[c * 2048 + wave * 512]);
            gl_lds16(bG + c * (32 * KD), &bS[c * 2048 + wave * 512]);
        }
        __syncthreads();   // drains vmcnt -> LDS valid
        aG += 64;
        bG += 64;

        #pragma unroll
        for (int ks = 0; ks < 2; ks++) {
            bf16x8 af[4], bf[4];
            const int cp = ((ks * 4 + quad) ^ (row & 7)) * 8;   // swizzled read chunk
            #pragma unroll
            for (int t = 0; t < 4; t++) {
                af[t] = *(const bf16x8*)(aS + (wm * 64 + t * 16 + row) * 64 + cp);
                bf[t] = *(const bf16x8*)(bS + (wn * 64 + t * 16 + row) * 64 + cp);
            }
            #pragma unroll
            for (int i = 0; i < 4; i++)
                #pragma unroll
                for (int j = 0; j < 4; j++)
                    acc[i][j] = __builtin_amdgcn_mfma_f32_16x16x32_bf16(af[i], bf[j], acc[i][j], 0, 0, 0);
        }
    }

    if (MODE == 0) {
        #pragma unroll
        for (int j = 0; j < 4; j++) {
            const int n  = n0 + wn * 64 + j * 16 + row;
            const float bi = bias[n];
            const int which = n >> 10;
            const int rem   = n & 1023;
            const int h     = rem >> 6;
            const int d     = rem & 63;
            #pragma unroll
            for (int i = 0; i < 4; i++) {
                const int mbase = m0 + wm * 64 + i * 16 + quad * 4;
                #pragma unroll
                for (int r = 0; r < 4; r++) {
                    const int m = mbase + r;
                    const int b = m >> 11;
                    const int t = m & 2047;
                    const int bh = b * NHEADS + h;
                    const float v = acc[i][j][r] + bi;
                    if (which == 0) {
                        Oq[((size_t)bh * T_SEQ + t) * HDIM + d] = f2b(v * QSCALE);
                    } else if (which == 1) {
                        Ok[((size_t)bh * T_SEQ + t) * HDIM + d] = f2b(v);
                    } else {
                        Ov[((size_t)bh * HDIM + d) * T_SEQ + t] = f2b(v);
                    }
                }
            }
        }
    } else {
        #pragma unroll
        for (int j = 0; j < 4; j++) {
            const int n  = n0 + wn * 64 + j * 16 + row;
            const float bi = bias[n];
            #pragma unroll
            for (int i = 0; i < 4; i++) {
                const int mbase = m0 + wm * 64 + i * 16 + quad * 4;
                #pragma unroll
                for (int r = 0; r < 4; r++)
                    Of[(size_t)(mbase + r) * NCOLS + n] = acc[i][j][r] + bi;
            }
        }
    }
}

// ---------------------------------------------------------------------------
// MFMA flash attention — R19 (verified, attn ~<90us): ONE tile per wave,
// one-sided blocks. Block (bh, by): i = 15-by (longest first), q-rows
// [128i, 128i+128), 8 waves x 16 rows; kend = 128(i+1). 1024 blocks ->
// 4 blocks/CU -> up to 32 waves/CU. Head-locality note: linear id = bh+64y,
// so all 16 blocks of head bh land on XCD bh%8 — K/V panels are already
// XCD-local; do not remap. Defer-max + tree-max kept; no setprio.
// ---------------------------------------------------------------------------
__global__ __launch_bounds__(512, 4) void attn_mfma(
    const unsigned short* __restrict__ Q,   // [bh][t][64] bf16 (scaled, log2e)
    const unsigned short* __restrict__ K,   // [bh][t][64] bf16
    const unsigned short* __restrict__ VT,  // [bh][64][T] bf16
    unsigned short* __restrict__ Out)       // [B*T][DMODEL] bf16
{
    __shared__ __align__(16) unsigned short kS[2][64 * 72];
    __shared__ __align__(16) unsigned short vS[2][64 * 72];

    const int tid  = threadIdx.x;
    const int lane = tid & 63;
    const int wave = tid >> 6;       // 0..7
    const int row  = lane & 15;
    const int quad = lane >> 4;

    const int bh = blockIdx.x;
    const int b  = bh >> 4;
    const int h  = bh & 15;
    const int i  = 15 - (int)blockIdx.y;       // longest blocks first
    const int q0 = 128 * i + 16 * wave;        // this wave's 16 q-rows
    const int kend = 128 * i + 128;            // WG-uniform loop bound

    const size_t qkbase = (size_t)bh * T_SEQ * HDIM;
    const size_t vtbase = (size_t)bh * HDIM * T_SEQ;

    // staging geometry: 512 threads cover one 64x64 tile per operand
    const int krow0 = tid >> 3;          // 0..63
    const int c0    = tid & 7;           // 0..7
    const int lds0  = krow0 * 72 + c0 * 8;
    const int flat0 = tid * 8;           // = krow0*64 + c0*8

    // Q fragments
    const unsigned short* qp = Q + qkbase + (size_t)(q0 + row) * HDIM + quad * 8;
    const bf16x8 qf0 = *(const bf16x8*)qp;
    const bf16x8 qf1 = *(const bf16x8*)(qp + 32);

    const f32x4 z = {0.f, 0.f, 0.f, 0.f};
    f32x4 o[4] = {z, z, z, z};
    float m_ = -1e30f, l_ = 0.f;

    // prefetch tile 0
    uint4 pk0 = *(const uint4*)(K  + qkbase + flat0);
    uint4 pv0 = *(const uint4*)(VT + vtbase + (size_t)krow0 * T_SEQ + c0 * 8);

    int buf = 0;
    for (int kb = 0; kb < kend; kb += 64) {
        // write staged tile to LDS[buf]
        *(uint4*)&kS[buf][lds0] = pk0;
        *(uint4*)&vS[buf][lds0] = pv0;
        __syncthreads();

        // prefetch next tile (overlaps with compute below)
        if (kb + 64 < kend) {
            const int kn = kb + 64;
            pk0 = *(const uint4*)(K  + qkbase + (size_t)kn * HDIM + flat0);
            pv0 = *(const uint4*)(VT + vtbase + (size_t)krow0 * T_SEQ + kn + c0 * 8);
        }

        const bool act = (kb <= q0);         // wave-uniform

        if (act) {
            // ---- QK^T from LDS K tile ----
            f32x4 sg[4];
            bf16x4 pf[4];
            #pragma unroll
            for (int s = 0; s < 4; s++) {
                const int kbs = kb + s * 16;
                if (kbs <= q0) {
                    const unsigned short* kp = &kS[buf][(s * 16 + row) * 72 + quad * 8];
                    const bf16x8 kf0 = *(const bf16x8*)kp;
                    const bf16x8 kf1 = *(const bf16x8*)(kp + 32);
                    f32x4 t = z;
                    t = __builtin_amdgcn_mfma_f32_16x16x32_bf16(kf0, qf0, t, 0, 0, 0);
                    t = __builtin_amdgcn_mfma_f32_16x16x32_bf16(kf1, qf1, t, 0, 0, 0);
                    if (kbs == q0) {
                        #pragma unroll
                        for (int r = 0; r < 4; r++)
                            if (quad * 4 + r > row) t[r] = -1e30f;
                    }
                    sg[s] = t;
                } else {
                    #pragma unroll
                    for (int r = 0; r < 4; r++) sg[s][r] = -1e30f;
                }
            }
            online_softmax(sg, m_, l_, o, pf);

            // ---- PV from LDS V^T tile ----
            #pragma unroll
            for (int s = 0; s < 4; s++) {
                const int kbs = kb + s * 16;
                if (kbs <= q0) {
                    #pragma unroll
                    for (int dt = 0; dt < 4; dt++) {
                        const bf16x4 vf = *(const bf16x4*)&vS[buf][
                            (dt * 16 + row) * 72 + (s * 2 + (quad >> 1)) * 8 + (quad & 1) * 4];
                        o[dt] = __builtin_amdgcn_mfma_f32_16x16x16bf16_1k(vf, pf[s], o[dt], 0, 0, 0);
                    }
                }
            }
        }

        buf ^= 1;
    }

    // ---- epilogue ----
    {
        const float rl = 1.f / l_;
        unsigned short* op = Out + ((size_t)(b * T_SEQ + q0 + row)) * DMODEL + h * HDIM + quad * 4;
        #pragma unroll
        for (int dt = 0; dt < 4; dt++) {
            uint2 u;
            u.x = pack2(o[dt][0] * rl, o[dt][1] * rl);
            u.y = pack2(o[dt][2] * rl, o[dt][3] * rl);
            *(uint2*)(op + dt * 16) = u;
        }
    }
}

extern "C" void kernel_launch(void* const* d_in, const int* in_sizes, int n_in,
                              void* d_out, int out_size, void* d_ws, size_t ws_size,
                              hipStream_t stream)
{
    const float* x    = (const float*)d_in[0];
    const float* Wqkv = (const float*)d_in[1];
    const float* bqkv = (const float*)d_in[2];
    const float* Wout = (const float*)d_in[3];
    const float* bout = (const float*)d_in[4];
    float* out = (float*)d_out;

    // workspace (MiB offsets): xb 0..16 | WqkvT 16..22 | WoutT 22..24 |
    // Qb 24..40 | Kb 40..56 | Vt 56..72 | Ab 72..88
    char* ws = (char*)d_ws;
    unsigned short* xb    = (unsigned short*)(ws + (size_t)0  * 1024 * 1024);
    unsigned short* WqkvT = (unsigned short*)(ws + (size_t)16 * 1024 * 1024);
    unsigned short* WoutT = (unsigned short*)(ws + (size_t)22 * 1024 * 1024);
    unsigned short* Qb    = (unsigned short*)(ws + (size_t)24 * 1024 * 1024);
    unsigned short* Kb    = (unsigned short*)(ws + (size_t)40 * 1024 * 1024);
    unsigned short* Vt    = (unsigned short*)(ws + (size_t)56 * 1024 * 1024);
    unsigned short* Ab    = (unsigned short*)(ws + (size_t)72 * 1024 * 1024);

    // 0) converts / transposes
    cvt_bf16<<<dim3(MROWS * DMODEL / 1024), 256, 0, stream>>>(x, xb, MROWS * DMODEL);
    cvt_tr<<<dim3(3 * DMODEL / 32, DMODEL / 32), 256, 0, stream>>>(Wqkv, WqkvT, DMODEL, 3 * DMODEL);
    cvt_tr<<<dim3(DMODEL / 32, DMODEL / 32), 256, 0, stream>>>(Wout, WoutT, DMODEL, DMODEL);

    // 1) qkv = x @ W_qkv + b_qkv -> Qb (scaled, log2e folded), Kb, Vt
    gemm_mfma<DMODEL, 3 * DMODEL, 0><<<dim3(3 * DMODEL / 128, MROWS / 128), 256, 0, stream>>>(
        xb, WqkvT, bqkv, Qb, Kb, Vt, nullptr);

    // 2) causal MFMA flash attention -> Ab bf16 (16 blocks/head, 8 waves, 1 tile/wave)
    attn_mfma<<<dim3(BATCH * NHEADS, 16), 512, 0, stream>>>(Qb, Kb, Vt, Ab);

    // 3) out = Ab @ W_out + b_out (fp32 out)
    gemm_mfma<DMODEL, DMODEL, 1><<<dim3(DMODEL / 128, MROWS / 128), 256, 0, stream>>>(
        Ab, WoutT, bout, nullptr, nullptr, nullptr, out);
}